// Round 13
// baseline (604.331 us; speedup 1.0000x reference)
//
#include <hip/hip_runtime.h>
#include <cstdint>
#include <cstddef>

#define ALPHA 1.702f
#define LIMIT 7.0f

#define NTOK 2048
#define HDIM 2048
#define IDIM 2048
#define I2   4096
#define NEXP 8

typedef float f32x4 __attribute__((ext_vector_type(4)));
typedef short bf16x8 __attribute__((ext_vector_type(8)));
typedef unsigned short u16;

__device__ __forceinline__ u16 f2bf(float f) {
  unsigned u = __float_as_uint(f);
  u += 0x7fffu + ((u >> 16) & 1u);   // RNE
  return (u16)(u >> 16);
}

__device__ __forceinline__ void gload_lds16(const void* g, void* l) {
  __builtin_amdgcn_global_load_lds(
      (const __attribute__((address_space(1))) void*)g,
      (__attribute__((address_space(3))) void*)l, 16, 0, 0);
}

#define BARRIER() do { asm volatile("" ::: "memory"); __builtin_amdgcn_s_barrier(); asm volatile("" ::: "memory"); } while (0)
#define VMCNT(n)  asm volatile("s_waitcnt vmcnt(" #n ")" ::: "memory")

// ---------------- x: fp32 -> bf16 ----------------
__global__ __launch_bounds__(256) void k_cvt(const float* __restrict__ in,
                                             u16* __restrict__ out) {
  int i = blockIdx.x * blockDim.x + threadIdx.x;
  const float4* p = (const float4*)in + (size_t)i * 2;
  float4 a = p[0], b = p[1];
  union { u16 s[8]; uint4 v; } o;
  o.s[0] = f2bf(a.x); o.s[1] = f2bf(a.y); o.s[2] = f2bf(a.z); o.s[3] = f2bf(a.w);
  o.s[4] = f2bf(b.x); o.s[5] = f2bf(b.y); o.s[6] = f2bf(b.z); o.s[7] = f2bf(b.w);
  ((uint4*)out)[i] = o.v;
}

// ------------- transpose + convert: (R,C) fp32 -> (C,R) bf16, 64x64 tiles (r12-verified) -------------
__global__ __launch_bounds__(256) void k_tc(const float* __restrict__ in,
                                            u16* __restrict__ out, int R, int C) {
  __shared__ float tile[64][65];
  const size_t mo = (size_t)blockIdx.z * R * C;
  const float* ip = in + mo;
  u16* op = out + mo;
  const int c0 = blockIdx.x * 64, r0 = blockIdx.y * 64;
  const int t = threadIdx.x;
  const int tr = t >> 4;
  const int tc = (t & 15) * 4;
#pragma unroll
  for (int i = 0; i < 4; ++i) {
    float4 v = *(const float4*)&ip[(size_t)(r0 + tr + i * 16) * C + c0 + tc];
    tile[tr + i * 16][tc] = v.x; tile[tr + i * 16][tc + 1] = v.y;
    tile[tr + i * 16][tc + 2] = v.z; tile[tr + i * 16][tc + 3] = v.w;
  }
  __syncthreads();
  const int cc = t >> 2;
  const int rb = (t & 3) * 8;
#pragma unroll
  for (int i = 0; i < 2; ++i) {
    int r = rb + i * 32;
    union { u16 s[8]; uint4 v; } o;
#pragma unroll
    for (int j = 0; j < 8; ++j) o.s[j] = f2bf(tile[r + j][cc]);
    *(uint4*)&op[(size_t)(c0 + cc) * R + r0 + r] = o.v;
  }
}

// ======== GEMM1: 128x128 tile, 4 waves, BK=32, m97 structure + XOR swizzle + XCD locality ========
// Swizzle (r9/r10-verified, 0 conflicts): LDS[row][slot s] holds global k-slot s ^ ((row>>1)&3).
// Co-residency: 16KB LDS, VGPR cap 170 -> ~3 blocks/CU; cross-block overlap fills barrier drains.
__global__ __launch_bounds__(256, 3) void k_gemm1(const u16* __restrict__ xbf,
                                                  const u16* __restrict__ w1t,
                                                  const float* __restrict__ gub,
                                                  const float* __restrict__ rw,
                                                  u16* __restrict__ inter) {
  __shared__ __align__(16) u16 As[128 * 32];
  __shared__ __align__(16) u16 Bs[128 * 32];

  const int bid = (int)blockIdx.x;
  const int L = (bid & 7) * 512 + (bid >> 3);           // XCD x owns expert x entirely
  const int mtile = L & 15, ntile = (L >> 4) & 31, e = L >> 9;
  const int row0 = mtile * 128, col0 = ntile * 128;
  const u16* A = xbf;
  const u16* B = w1t + (size_t)e * I2 * HDIM;

  const int tid = threadIdx.x;
  const int w = tid >> 6, lane = tid & 63;
  const int wr = w >> 1, wc = w & 1;
  const int rrow = lane & 15, klane = lane >> 4;
  const int kofs = ((klane ^ ((rrow >> 1) & 3)) << 3);

  // staging: 512 chunks of 16B; instr (w,j) covers chunks (w*2+j)*64 + lane
  auto stA = [&](int k0) {
#pragma unroll
    for (int j = 0; j < 2; ++j) {
      int c = (w * 2 + j) * 64 + lane;
      int r = c >> 2, g = c & 3;
      int ks = ((g ^ ((r >> 1) & 3)) << 3);
      gload_lds16(A + (size_t)(row0 + r) * HDIM + k0 + ks,
                  &As[(size_t)(w * 2 + j) * 512]);
    }
  };
  auto stB = [&](int k0) {
#pragma unroll
    for (int j = 0; j < 2; ++j) {
      int c = (w * 2 + j) * 64 + lane;
      int r = c >> 2, g = c & 3;
      int ks = ((g ^ ((r >> 1) & 3)) << 3);
      gload_lds16(B + (size_t)(col0 + r) * HDIM + k0 + ks,
                  &Bs[(size_t)(w * 2 + j) * 512]);
    }
  };

  f32x4 acc[4][4];
#pragma unroll
  for (int m = 0; m < 4; m++)
#pragma unroll
    for (int n = 0; n < 4; n++) acc[m][n] = (f32x4){0.f, 0.f, 0.f, 0.f};

  for (int k0 = 0; k0 < HDIM; k0 += 32) {
    stA(k0); stB(k0);
    __syncthreads();                 // vmcnt(0)+lgkmcnt(0) drain + barrier (m97 semantics)
    bf16x8 a[4], b[4];
#pragma unroll
    for (int m = 0; m < 4; m++)
      a[m] = *(const bf16x8*)&As[(wr * 64 + m * 16 + rrow) * 32 + kofs];
#pragma unroll
    for (int n = 0; n < 4; n++)
      b[n] = *(const bf16x8*)&Bs[(wc * 64 + n * 16 + rrow) * 32 + kofs];
#pragma unroll
    for (int m = 0; m < 4; m++)
#pragma unroll
      for (int n = 0; n < 4; n++)
        acc[m][n] = __builtin_amdgcn_mfma_f32_16x16x32_bf16(a[m], b[n], acc[m][n], 0, 0, 0);
    __syncthreads();                 // protect LDS before next stage
  }

  // epilogue (r1-verified): bias, gate/up shfl pairing, activation, rw fold
  const float* bias = gub + (size_t)e * I2;
  u16* ip = inter + (size_t)e * NTOK * IDIM;
  float bv[4];
  int cols[4];
#pragma unroll
  for (int n = 0; n < 4; n++) {
    cols[n] = col0 + wc * 64 + n * 16 + rrow;
    bv[n] = bias[cols[n]];
  }
#pragma unroll
  for (int m = 0; m < 4; m++) {
#pragma unroll
    for (int r = 0; r < 4; r++) {
      int row = row0 + wr * 64 + m * 16 + klane * 4 + r;
      float wgt = rw[row * NEXP + e];
#pragma unroll
      for (int n = 0; n < 4; n++) {
        float gu = acc[m][n][r] + bv[n];
        float pg = __shfl_xor(gu, 1);
        float gate = (lane & 1) ? pg : gu;
        float up   = (lane & 1) ? gu : pg;
        gate = fminf(gate, LIMIT);
        up = fminf(fmaxf(up, -LIMIT), LIMIT);
        float glu = gate / (1.f + __expf(-ALPHA * gate));
        float val = (up + 1.f) * glu * wgt;
        if (!(lane & 1))
          ip[(size_t)row * IDIM + (cols[n] >> 1)] = f2bf(val);
      }
    }
  }
}

// ======================= 256x256 8-wave 8-phase GEMM core (r5-verified) =======================
#define MFMA_Q(mh, nh, bb) \
  _Pragma("unroll") for (int mm = 0; mm < 4; ++mm) \
  _Pragma("unroll") for (int nn = 0; nn < 2; ++nn) \
  _Pragma("unroll") for (int ks = 0; ks < 2; ++ks) \
    acc[(mh)*4+mm][(nh)*2+nn] = __builtin_amdgcn_mfma_f32_16x16x32_bf16( \
        a[mm][ks], (bb)[nn][ks], acc[(mh)*4+mm][(nh)*2+nn], 0, 0, 0);

// ---------------- GEMM2: 256x256 8-phase, split-K=4 (2 experts per split) ----------------
__global__ __launch_bounds__(512, 2) void k_gemm2(const u16* __restrict__ inter,
                                                  const u16* __restrict__ w2t,
                                                  float* __restrict__ part) {
  __shared__ __align__(16) u16 Als[4][128 * 64];
  __shared__ __align__(16) u16 Bls[4][128 * 64];

  const int bid = (int)blockIdx.x;
  const int L = (bid & 7) * 32 + (bid >> 3);
  const int mtile = L & 7, ntile = (L >> 3) & 7, sp = L >> 6;
  const int row0 = mtile * 256, col0 = ntile * 256;
  const int es = sp * 2;

  const int tid = threadIdx.x;
  const int w = tid >> 6, lane = tid & 63;
  const int wr = w >> 2, wc = w & 3;
  const int rrow = lane & 15, klane = lane >> 4;
  const int sA = (wr * 64 + rrow) * 64;
  const int sB = (wc * 32 + rrow) * 64;
  int kofs[2];
  kofs[0] = ((klane ^ (rrow & 7)) << 3);
  kofs[1] = (((4 + klane) ^ (rrow & 7)) << 3);

  auto stA = [&](int reg, int h, int k0) {
    const u16* Ab = inter + (size_t)(es + (k0 >> 11)) * NTOK * IDIM;
    const int kk = k0 & 2047;
#pragma unroll
    for (int j = 0; j < 2; ++j) {
      int c = (w * 2 + j) * 64 + lane;
      int r = c >> 3, gg = c & 7;
      int ksw = ((gg ^ (r & 7)) << 3);
      int R = ((r >> 6) << 7) + h * 64 + (r & 63);
      gload_lds16(Ab + (size_t)(row0 + R) * IDIM + kk + ksw,
                  &Als[reg][(size_t)(w * 2 + j) * 512]);
    }
  };
  auto stB = [&](int reg, int h, int k0) {
    const u16* Bb = w2t + (size_t)(es + (k0 >> 11)) * HDIM * IDIM;
    const int kk = k0 & 2047;
#pragma unroll
    for (int j = 0; j < 2; ++j) {
      int c = (w * 2 + j) * 64 + lane;
      int r = c >> 3, gg = c & 7;
      int ksw = ((gg ^ (r & 7)) << 3);
      int C = ((r >> 5) << 6) + h * 32 + (r & 31);
      gload_lds16(Bb + (size_t)(col0 + C) * IDIM + kk + ksw,
                  &Bls[reg][(size_t)(w * 2 + j) * 512]);
    }
  };

  f32x4 acc[8][4];
#pragma unroll
  for (int i = 0; i < 8; ++i)
#pragma unroll
    for (int j = 0; j < 4; ++j) acc[i][j] = (f32x4){0.f, 0.f, 0.f, 0.f};

  bf16x8 a[4][2], b0[2][2], b1[2][2];
  auto rdA = [&](int reg) {
#pragma unroll
    for (int mm = 0; mm < 4; ++mm)
#pragma unroll
      for (int ks = 0; ks < 2; ++ks)
        a[mm][ks] = *(const bf16x8*)&Als[reg][sA + mm * 1024 + kofs[ks]];
  };
  auto rdB0 = [&](int reg) {
#pragma unroll
    for (int nn = 0; nn < 2; ++nn)
#pragma unroll
      for (int ks = 0; ks < 2; ++ks)
        b0[nn][ks] = *(const bf16x8*)&Bls[reg][sB + nn * 1024 + kofs[ks]];
  };
  auto rdB1 = [&](int reg) {
#pragma unroll
    for (int nn = 0; nn < 2; ++nn)
#pragma unroll
      for (int ks = 0; ks < 2; ++ks)
        b1[nn][ks] = *(const bf16x8*)&Bls[reg][sB + nn * 1024 + kofs[ks]];
  };

  stB(0, 0, 0); stB(1, 1, 0); stA(0, 0, 0); stA(1, 1, 0);
  stB(2, 0, 64); stB(3, 1, 64); stA(2, 0, 64);
  VMCNT(8);
  BARRIER();

  for (int i = 0; i < 32; ++i) {
    const int t = 2 * i;
    const int kA1 = (t + 1) * 64;
    const int kN0 = (t + 2 < 64 ? t + 2 : 63) * 64;
    const int kN1 = (t + 3 < 64 ? t + 3 : 63) * 64;

    rdA(0); rdB0(0);
    stA(3, 1, kA1);
    BARRIER();
    __builtin_amdgcn_s_setprio(1); MFMA_Q(0, 0, b0); __builtin_amdgcn_s_setprio(0);
    BARRIER();

    rdB1(1);
    stB(0, 0, kN0);
    BARRIER();
    __builtin_amdgcn_s_setprio(1); MFMA_Q(0, 1, b1); __builtin_amdgcn_s_setprio(0);
    VMCNT(10);
    BARRIER();

    rdA(1);
    stB(1, 1, kN0);
    BARRIER();
    __builtin_amdgcn_s_setprio(1); MFMA_Q(1, 0, b0); __builtin_amdgcn_s_setprio(0);
    BARRIER();

    stA(0, 0, kN0);
    BARRIER();
    __builtin_amdgcn_s_setprio(1); MFMA_Q(1, 1, b1); __builtin_amdgcn_s_setprio(0);
    VMCNT(8);
    BARRIER();

    rdA(2); rdB0(2);
    stA(1, 1, kN0);
    BARRIER();
    __builtin_amdgcn_s_setprio(1); MFMA_Q(0, 0, b0); __builtin_amdgcn_s_setprio(0);
    BARRIER();

    rdB1(3);
    stB(2, 0, kN1);
    BARRIER();
    __builtin_amdgcn_s_setprio(1); MFMA_Q(0, 1, b1); __builtin_amdgcn_s_setprio(0);
    VMCNT(10);
    BARRIER();

    rdA(3);
    stB(3, 1, kN1);
    BARRIER();
    __builtin_amdgcn_s_setprio(1); MFMA_Q(1, 0, b0); __builtin_amdgcn_s_setprio(0);
    BARRIER();

    stA(2, 0, kN1);
    BARRIER();
    __builtin_amdgcn_s_setprio(1); MFMA_Q(1, 1, b1); __builtin_amdgcn_s_setprio(0);
    VMCNT(8);
    BARRIER();
  }

  float* pp = part + (size_t)sp * NTOK * HDIM;
#pragma unroll
  for (int ai = 0; ai < 8; ++ai) {
    const int mh = ai >> 2, mm = ai & 3;
#pragma unroll
    for (int bj = 0; bj < 4; ++bj) {
      const int nh = bj >> 1, nn = bj & 1;
      const int col = col0 + wc * 64 + nh * 32 + nn * 16 + rrow;
#pragma unroll
      for (int r = 0; r < 4; ++r) {
        const int row = row0 + wr * 128 + mh * 64 + mm * 16 + klane * 4 + r;
        pp[(size_t)row * HDIM + col] = acc[ai][bj][r];
      }
    }
  }
}

// ---------------- reduce: out = sum_splits partial + sum_e rw*down_bias ----------------
__global__ __launch_bounds__(256) void k_reduce(const float* __restrict__ part,
                                                const float* __restrict__ dbias,
                                                const float* __restrict__ rw,
                                                float* __restrict__ out) {
  const int i = blockIdx.x * 256 + threadIdx.x;
  const int i4 = i * 4;
  const int n = i4 >> 11;
  const int h = i4 & 2047;
  const size_t MSZ = (size_t)NTOK * HDIM / 4;
  const float4* p = (const float4*)part;
  float4 v0 = p[i];
  float4 v1 = p[i + MSZ];
  float4 v2 = p[i + 2 * MSZ];
  float4 v3 = p[i + 3 * MSZ];
  float4 s;
  s.x = (v0.x + v1.x) + (v2.x + v3.x);
  s.y = (v0.y + v1.y) + (v2.y + v3.y);
  s.z = (v0.z + v1.z) + (v2.z + v3.z);
  s.w = (v0.w + v1.w) + (v2.w + v3.w);
#pragma unroll
  for (int e = 0; e < NEXP; ++e) {
    float rwe = rw[n * NEXP + e];
    float4 db = *(const float4*)&dbias[(size_t)e * HDIM + h];
    s.x += rwe * db.x; s.y += rwe * db.y;
    s.z += rwe * db.z; s.w += rwe * db.w;
  }
  *(float4*)&out[i4] = s;
}

extern "C" void kernel_launch(void* const* d_in, const int* in_sizes, int n_in,
                              void* d_out, int out_size, void* d_ws, size_t ws_size,
                              hipStream_t stream) {
  const float* hs   = (const float*)d_in[0];
  const float* rw   = (const float*)d_in[1];
  const float* gup  = (const float*)d_in[2];
  const float* gupb = (const float*)d_in[3];
  const float* dwn  = (const float*)d_in[4];
  const float* dwnb = (const float*)d_in[5];
  float* out = (float*)d_out;

  u16* xbf   = (u16*)d_ws;
  u16* w1t   = xbf + (size_t)NTOK * HDIM;
  u16* w2t   = w1t + (size_t)NEXP * I2 * HDIM;
  u16* inter = w2t + (size_t)NEXP * HDIM * IDIM;
  float* part = (float*)w1t;
  size_t need = ((size_t)NTOK * HDIM + (size_t)NEXP * I2 * HDIM +
                 (size_t)NEXP * HDIM * IDIM + (size_t)NEXP * NTOK * IDIM) * 2;
  if (ws_size < need) return;

  k_cvt<<<(NTOK * HDIM) / (256 * 8), 256, 0, stream>>>(hs, xbf);

  dim3 g1(I2 / 64, HDIM / 64, NEXP);
  k_tc<<<g1, 256, 0, stream>>>(gup, w1t, HDIM, I2);
  dim3 g2(HDIM / 64, IDIM / 64, NEXP);
  k_tc<<<g2, 256, 0, stream>>>(dwn, w2t, IDIM, HDIM);

  k_gemm1<<<dim3(4096), 256, 0, stream>>>(xbf, w1t, gupb, rw, inter);

  k_gemm2<<<dim3(256), 512, 0, stream>>>(inter, w2t, part);

  k_reduce<<<dim3(NTOK * HDIM / 1024), 256, 0, stream>>>(part, dwnb, rw, out);
}

// Round 14
// 557.334 us; speedup vs baseline: 1.0843x; 1.0843x over previous
//
#include <hip/hip_runtime.h>
#include <cstdint>
#include <cstddef>

#define ALPHA 1.702f
#define LIMIT 7.0f

#define NTOK 2048
#define HDIM 2048
#define IDIM 2048
#define I2   4096
#define NEXP 8

typedef float f32x4 __attribute__((ext_vector_type(4)));
typedef short bf16x8 __attribute__((ext_vector_type(8)));
typedef unsigned short u16;

__device__ __forceinline__ u16 f2bf(float f) {
  unsigned u = __float_as_uint(f);
  u += 0x7fffu + ((u >> 16) & 1u);   // RNE
  return (u16)(u >> 16);
}

__device__ __forceinline__ void gload_lds16(const void* g, void* l) {
  __builtin_amdgcn_global_load_lds(
      (const __attribute__((address_space(1))) void*)g,
      (__attribute__((address_space(3))) void*)l, 16, 0, 0);
}

#define BARRIER() do { asm volatile("" ::: "memory"); __builtin_amdgcn_s_barrier(); asm volatile("" ::: "memory"); } while (0)
#define VMCNT(n)  asm volatile("s_waitcnt vmcnt(" #n ")" ::: "memory")

// ---------------- x: fp32 -> bf16 ----------------
__global__ __launch_bounds__(256) void k_cvt(const float* __restrict__ in,
                                             u16* __restrict__ out) {
  int i = blockIdx.x * blockDim.x + threadIdx.x;
  const float4* p = (const float4*)in + (size_t)i * 2;
  float4 a = p[0], b = p[1];
  union { u16 s[8]; uint4 v; } o;
  o.s[0] = f2bf(a.x); o.s[1] = f2bf(a.y); o.s[2] = f2bf(a.z); o.s[3] = f2bf(a.w);
  o.s[4] = f2bf(b.x); o.s[5] = f2bf(b.y); o.s[6] = f2bf(b.z); o.s[7] = f2bf(b.w);
  ((uint4*)out)[i] = o.v;
}

// ------------- transpose + convert: (R,C) fp32 -> (C,R) bf16, 64x64 tiles (r12-verified) -------------
__global__ __launch_bounds__(256) void k_tc(const float* __restrict__ in,
                                            u16* __restrict__ out, int R, int C) {
  __shared__ float tile[64][65];
  const size_t mo = (size_t)blockIdx.z * R * C;
  const float* ip = in + mo;
  u16* op = out + mo;
  const int c0 = blockIdx.x * 64, r0 = blockIdx.y * 64;
  const int t = threadIdx.x;
  const int tr = t >> 4;
  const int tc = (t & 15) * 4;
#pragma unroll
  for (int i = 0; i < 4; ++i) {
    float4 v = *(const float4*)&ip[(size_t)(r0 + tr + i * 16) * C + c0 + tc];
    tile[tr + i * 16][tc] = v.x; tile[tr + i * 16][tc + 1] = v.y;
    tile[tr + i * 16][tc + 2] = v.z; tile[tr + i * 16][tc + 3] = v.w;
  }
  __syncthreads();
  const int cc = t >> 2;
  const int rb = (t & 3) * 8;
#pragma unroll
  for (int i = 0; i < 2; ++i) {
    int r = rb + i * 32;
    union { u16 s[8]; uint4 v; } o;
#pragma unroll
    for (int j = 0; j < 8; ++j) o.s[j] = f2bf(tile[r + j][cc]);
    *(uint4*)&op[(size_t)(c0 + cc) * R + r0 + r] = o.v;
  }
}

// ======================= 256x256 8-wave 8-phase GEMM core (r5/r12 skeleton) =======================
// MFMA_Q: ks OUTERMOST -> dep distance 8 between reuses of the same accumulator
// (previous ks-innermost had back-to-back dependent MFMA pairs on each acc).
#define MFMA_Q(mh, nh, bb) \
  _Pragma("unroll") for (int ks = 0; ks < 2; ++ks) \
  _Pragma("unroll") for (int mm = 0; mm < 4; ++mm) \
  _Pragma("unroll") for (int nn = 0; nn < 2; ++nn) \
    acc[(mh)*4+mm][(nh)*2+nn] = __builtin_amdgcn_mfma_f32_16x16x32_bf16( \
        a[mm][ks], (bb)[nn][ks], acc[(mh)*4+mm][(nh)*2+nn], 0, 0, 0);

// ---------------- GEMM1: gate_up + activation + rw fold ----------------
__global__ __launch_bounds__(512, 2) void k_gemm1(const u16* __restrict__ xbf,
                                                  const u16* __restrict__ w1t,
                                                  const float* __restrict__ gub,
                                                  const float* __restrict__ rw,
                                                  u16* __restrict__ inter) {
  __shared__ __align__(16) u16 Als[4][128 * 64];
  __shared__ __align__(16) u16 Bls[4][128 * 64];

  const int bid = (int)blockIdx.x;
  const int L = (bid & 7) * 128 + (bid >> 3);
  const int mtile = L & 7, ntile = (L >> 3) & 15, e = L >> 7;
  const int row0 = mtile * 256, col0 = ntile * 256;
  const u16* A = xbf;
  const u16* B = w1t + (size_t)e * I2 * HDIM;

  const int tid = threadIdx.x;
  const int w = tid >> 6, lane = tid & 63;
  const int wr = w >> 2, wc = w & 3;
  const int rrow = lane & 15, klane = lane >> 4;
  const int sA = (wr * 64 + rrow) * 64;
  const int sB = (wc * 32 + rrow) * 64;
  int kofs[2];
  kofs[0] = ((klane ^ (rrow & 7)) << 3);
  kofs[1] = (((4 + klane) ^ (rrow & 7)) << 3);

  auto stA = [&](int reg, int h, int k0) {
#pragma unroll
    for (int j = 0; j < 2; ++j) {
      int c = (w * 2 + j) * 64 + lane;
      int r = c >> 3, gg = c & 7;
      int ksw = ((gg ^ (r & 7)) << 3);
      int R = ((r >> 6) << 7) + h * 64 + (r & 63);
      gload_lds16(A + (size_t)(row0 + R) * HDIM + k0 + ksw,
                  &Als[reg][(size_t)(w * 2 + j) * 512]);
    }
  };
  auto stB = [&](int reg, int h, int k0) {
#pragma unroll
    for (int j = 0; j < 2; ++j) {
      int c = (w * 2 + j) * 64 + lane;
      int r = c >> 3, gg = c & 7;
      int ksw = ((gg ^ (r & 7)) << 3);
      int C = ((r >> 5) << 6) + h * 32 + (r & 31);
      gload_lds16(B + (size_t)(col0 + C) * HDIM + k0 + ksw,
                  &Bls[reg][(size_t)(w * 2 + j) * 512]);
    }
  };

  f32x4 acc[8][4];
#pragma unroll
  for (int i = 0; i < 8; ++i)
#pragma unroll
    for (int j = 0; j < 4; ++j) acc[i][j] = (f32x4){0.f, 0.f, 0.f, 0.f};

  bf16x8 a[4][2], b0[2][2], b1[2][2];
  auto rdA = [&](int reg) {
#pragma unroll
    for (int mm = 0; mm < 4; ++mm)
#pragma unroll
      for (int ks = 0; ks < 2; ++ks)
        a[mm][ks] = *(const bf16x8*)&Als[reg][sA + mm * 1024 + kofs[ks]];
  };
  auto rdB0 = [&](int reg) {
#pragma unroll
    for (int nn = 0; nn < 2; ++nn)
#pragma unroll
      for (int ks = 0; ks < 2; ++ks)
        b0[nn][ks] = *(const bf16x8*)&Bls[reg][sB + nn * 1024 + kofs[ks]];
  };
  auto rdB1 = [&](int reg) {
#pragma unroll
    for (int nn = 0; nn < 2; ++nn)
#pragma unroll
      for (int ks = 0; ks < 2; ++ks)
        b1[nn][ks] = *(const bf16x8*)&Bls[reg][sB + nn * 1024 + kofs[ks]];
  };

  stB(0, 0, 0); stB(1, 1, 0); stA(0, 0, 0); stA(1, 1, 0);
  stB(2, 0, 64); stB(3, 1, 64); stA(2, 0, 64);
  VMCNT(8);
  BARRIER();

  for (int i = 0; i < 16; ++i) {
    const int t = 2 * i;
    const int kA1 = (t + 1) * 64;
    const int kN0 = (t + 2 < 32 ? t + 2 : 31) * 64;
    const int kN1 = (t + 3 < 32 ? t + 3 : 31) * 64;

    rdA(0); rdB0(0);
    stA(3, 1, kA1);
    BARRIER();
    __builtin_amdgcn_s_setprio(1); MFMA_Q(0, 0, b0); __builtin_amdgcn_s_setprio(0);
    BARRIER();

    rdB1(1);
    stB(0, 0, kN0);
    BARRIER();
    __builtin_amdgcn_s_setprio(1); MFMA_Q(0, 1, b1); __builtin_amdgcn_s_setprio(0);
    VMCNT(10);
    BARRIER();

    rdA(1);
    stB(1, 1, kN0);
    BARRIER();
    __builtin_amdgcn_s_setprio(1); MFMA_Q(1, 0, b0); __builtin_amdgcn_s_setprio(0);
    BARRIER();

    stA(0, 0, kN0);
    BARRIER();
    __builtin_amdgcn_s_setprio(1); MFMA_Q(1, 1, b1); __builtin_amdgcn_s_setprio(0);
    VMCNT(8);
    BARRIER();

    rdA(2); rdB0(2);
    stA(1, 1, kN0);
    BARRIER();
    __builtin_amdgcn_s_setprio(1); MFMA_Q(0, 0, b0); __builtin_amdgcn_s_setprio(0);
    BARRIER();

    rdB1(3);
    stB(2, 0, kN1);
    BARRIER();
    __builtin_amdgcn_s_setprio(1); MFMA_Q(0, 1, b1); __builtin_amdgcn_s_setprio(0);
    VMCNT(10);
    BARRIER();

    rdA(3);
    stB(3, 1, kN1);
    BARRIER();
    __builtin_amdgcn_s_setprio(1); MFMA_Q(1, 0, b0); __builtin_amdgcn_s_setprio(0);
    BARRIER();

    stA(2, 0, kN1);
    BARRIER();
    __builtin_amdgcn_s_setprio(1); MFMA_Q(1, 1, b1); __builtin_amdgcn_s_setprio(0);
    VMCNT(8);
    BARRIER();
  }

  const float* bias = gub + (size_t)e * I2;
  u16* ip = inter + (size_t)e * NTOK * IDIM;
#pragma unroll
  for (int ai = 0; ai < 8; ++ai) {
    const int mh = ai >> 2, mm = ai & 3;
#pragma unroll
    for (int bj = 0; bj < 4; ++bj) {
      const int nh = bj >> 1, nn = bj & 1;
      const int col = col0 + wc * 64 + nh * 32 + nn * 16 + rrow;
      const float bv = bias[col];
#pragma unroll
      for (int r = 0; r < 4; ++r) {
        const int row = row0 + wr * 128 + mh * 64 + mm * 16 + klane * 4 + r;
        float gu = acc[ai][bj][r] + bv;
        float pg = __shfl_xor(gu, 1);
        float gate = (lane & 1) ? pg : gu;
        float up   = (lane & 1) ? gu : pg;
        gate = fminf(gate, LIMIT);
        up = fminf(fmaxf(up, -LIMIT), LIMIT);
        float glu = gate / (1.f + __expf(-ALPHA * gate));
        float val = (up + 1.f) * glu * rw[row * NEXP + e];
        if (!(lane & 1)) ip[(size_t)row * IDIM + (col >> 1)] = f2bf(val);
      }
    }
  }
}

// ---------------- GEMM2: 256x256 8-phase, split-K=4 (2 experts per split) ----------------
__global__ __launch_bounds__(512, 2) void k_gemm2(const u16* __restrict__ inter,
                                                  const u16* __restrict__ w2t,
                                                  float* __restrict__ part) {
  __shared__ __align__(16) u16 Als[4][128 * 64];
  __shared__ __align__(16) u16 Bls[4][128 * 64];

  const int bid = (int)blockIdx.x;
  const int L = (bid & 7) * 32 + (bid >> 3);
  const int mtile = L & 7, ntile = (L >> 3) & 7, sp = L >> 6;
  const int row0 = mtile * 256, col0 = ntile * 256;
  const int es = sp * 2;

  const int tid = threadIdx.x;
  const int w = tid >> 6, lane = tid & 63;
  const int wr = w >> 2, wc = w & 3;
  const int rrow = lane & 15, klane = lane >> 4;
  const int sA = (wr * 64 + rrow) * 64;
  const int sB = (wc * 32 + rrow) * 64;
  int kofs[2];
  kofs[0] = ((klane ^ (rrow & 7)) << 3);
  kofs[1] = (((4 + klane) ^ (rrow & 7)) << 3);

  auto stA = [&](int reg, int h, int k0) {
    const u16* Ab = inter + (size_t)(es + (k0 >> 11)) * NTOK * IDIM;
    const int kk = k0 & 2047;
#pragma unroll
    for (int j = 0; j < 2; ++j) {
      int c = (w * 2 + j) * 64 + lane;
      int r = c >> 3, gg = c & 7;
      int ksw = ((gg ^ (r & 7)) << 3);
      int R = ((r >> 6) << 7) + h * 64 + (r & 63);
      gload_lds16(Ab + (size_t)(row0 + R) * IDIM + kk + ksw,
                  &Als[reg][(size_t)(w * 2 + j) * 512]);
    }
  };
  auto stB = [&](int reg, int h, int k0) {
    const u16* Bb = w2t + (size_t)(es + (k0 >> 11)) * HDIM * IDIM;
    const int kk = k0 & 2047;
#pragma unroll
    for (int j = 0; j < 2; ++j) {
      int c = (w * 2 + j) * 64 + lane;
      int r = c >> 3, gg = c & 7;
      int ksw = ((gg ^ (r & 7)) << 3);
      int C = ((r >> 5) << 6) + h * 32 + (r & 31);
      gload_lds16(Bb + (size_t)(col0 + C) * IDIM + kk + ksw,
                  &Bls[reg][(size_t)(w * 2 + j) * 512]);
    }
  };

  f32x4 acc[8][4];
#pragma unroll
  for (int i = 0; i < 8; ++i)
#pragma unroll
    for (int j = 0; j < 4; ++j) acc[i][j] = (f32x4){0.f, 0.f, 0.f, 0.f};

  bf16x8 a[4][2], b0[2][2], b1[2][2];
  auto rdA = [&](int reg) {
#pragma unroll
    for (int mm = 0; mm < 4; ++mm)
#pragma unroll
      for (int ks = 0; ks < 2; ++ks)
        a[mm][ks] = *(const bf16x8*)&Als[reg][sA + mm * 1024 + kofs[ks]];
  };
  auto rdB0 = [&](int reg) {
#pragma unroll
    for (int nn = 0; nn < 2; ++nn)
#pragma unroll
      for (int ks = 0; ks < 2; ++ks)
        b0[nn][ks] = *(const bf16x8*)&Bls[reg][sB + nn * 1024 + kofs[ks]];
  };
  auto rdB1 = [&](int reg) {
#pragma unroll
    for (int nn = 0; nn < 2; ++nn)
#pragma unroll
      for (int ks = 0; ks < 2; ++ks)
        b1[nn][ks] = *(const bf16x8*)&Bls[reg][sB + nn * 1024 + kofs[ks]];
  };

  stB(0, 0, 0); stB(1, 1, 0); stA(0, 0, 0); stA(1, 1, 0);
  stB(2, 0, 64); stB(3, 1, 64); stA(2, 0, 64);
  VMCNT(8);
  BARRIER();

  for (int i = 0; i < 32; ++i) {
    const int t = 2 * i;
    const int kA1 = (t + 1) * 64;
    const int kN0 = (t + 2 < 64 ? t + 2 : 63) * 64;
    const int kN1 = (t + 3 < 64 ? t + 3 : 63) * 64;

    rdA(0); rdB0(0);
    stA(3, 1, kA1);
    BARRIER();
    __builtin_amdgcn_s_setprio(1); MFMA_Q(0, 0, b0); __builtin_amdgcn_s_setprio(0);
    BARRIER();

    rdB1(1);
    stB(0, 0, kN0);
    BARRIER();
    __builtin_amdgcn_s_setprio(1); MFMA_Q(0, 1, b1); __builtin_amdgcn_s_setprio(0);
    VMCNT(10);
    BARRIER();

    rdA(1);
    stB(1, 1, kN0);
    BARRIER();
    __builtin_amdgcn_s_setprio(1); MFMA_Q(1, 0, b0); __builtin_amdgcn_s_setprio(0);
    BARRIER();

    stA(0, 0, kN0);
    BARRIER();
    __builtin_amdgcn_s_setprio(1); MFMA_Q(1, 1, b1); __builtin_amdgcn_s_setprio(0);
    VMCNT(8);
    BARRIER();

    rdA(2); rdB0(2);
    stA(1, 1, kN0);
    BARRIER();
    __builtin_amdgcn_s_setprio(1); MFMA_Q(0, 0, b0); __builtin_amdgcn_s_setprio(0);
    BARRIER();

    rdB1(3);
    stB(2, 0, kN1);
    BARRIER();
    __builtin_amdgcn_s_setprio(1); MFMA_Q(0, 1, b1); __builtin_amdgcn_s_setprio(0);
    VMCNT(10);
    BARRIER();

    rdA(3);
    stB(3, 1, kN1);
    BARRIER();
    __builtin_amdgcn_s_setprio(1); MFMA_Q(1, 0, b0); __builtin_amdgcn_s_setprio(0);
    BARRIER();

    stA(2, 0, kN1);
    BARRIER();
    __builtin_amdgcn_s_setprio(1); MFMA_Q(1, 1, b1); __builtin_amdgcn_s_setprio(0);
    VMCNT(8);
    BARRIER();
  }

  float* pp = part + (size_t)sp * NTOK * HDIM;
#pragma unroll
  for (int ai = 0; ai < 8; ++ai) {
    const int mh = ai >> 2, mm = ai & 3;
#pragma unroll
    for (int bj = 0; bj < 4; ++bj) {
      const int nh = bj >> 1, nn = bj & 1;
      const int col = col0 + wc * 64 + nh * 32 + nn * 16 + rrow;
#pragma unroll
      for (int r = 0; r < 4; ++r) {
        const int row = row0 + wr * 128 + mh * 64 + mm * 16 + klane * 4 + r;
        pp[(size_t)row * HDIM + col] = acc[ai][bj][r];
      }
    }
  }
}

// ---------------- reduce: out = sum_splits partial + sum_e rw*down_bias ----------------
__global__ __launch_bounds__(256) void k_reduce(const float* __restrict__ part,
                                                const float* __restrict__ dbias,
                                                const float* __restrict__ rw,
                                                float* __restrict__ out) {
  const int i = blockIdx.x * 256 + threadIdx.x;
  const int i4 = i * 4;
  const int n = i4 >> 11;
  const int h = i4 & 2047;
  const size_t MSZ = (size_t)NTOK * HDIM / 4;
  const float4* p = (const float4*)part;
  float4 v0 = p[i];
  float4 v1 = p[i + MSZ];
  float4 v2 = p[i + 2 * MSZ];
  float4 v3 = p[i + 3 * MSZ];
  float4 s;
  s.x = (v0.x + v1.x) + (v2.x + v3.x);
  s.y = (v0.y + v1.y) + (v2.y + v3.y);
  s.z = (v0.z + v1.z) + (v2.z + v3.z);
  s.w = (v0.w + v1.w) + (v2.w + v3.w);
#pragma unroll
  for (int e = 0; e < NEXP; ++e) {
    float rwe = rw[n * NEXP + e];
    float4 db = *(const float4*)&dbias[(size_t)e * HDIM + h];
    s.x += rwe * db.x; s.y += rwe * db.y;
    s.z += rwe * db.z; s.w += rwe * db.w;
  }
  *(float4*)&out[i4] = s;
}

extern "C" void kernel_launch(void* const* d_in, const int* in_sizes, int n_in,
                              void* d_out, int out_size, void* d_ws, size_t ws_size,
                              hipStream_t stream) {
  const float* hs   = (const float*)d_in[0];
  const float* rw   = (const float*)d_in[1];
  const float* gup  = (const float*)d_in[2];
  const float* gupb = (const float*)d_in[3];
  const float* dwn  = (const float*)d_in[4];
  const float* dwnb = (const float*)d_in[5];
  float* out = (float*)d_out;

  u16* xbf   = (u16*)d_ws;
  u16* w1t   = xbf + (size_t)NTOK * HDIM;
  u16* w2t   = w1t + (size_t)NEXP * I2 * HDIM;
  u16* inter = w2t + (size_t)NEXP * HDIM * IDIM;
  float* part = (float*)w1t;
  size_t need = ((size_t)NTOK * HDIM + (size_t)NEXP * I2 * HDIM +
                 (size_t)NEXP * HDIM * IDIM + (size_t)NEXP * NTOK * IDIM) * 2;
  if (ws_size < need) return;

  k_cvt<<<(NTOK * HDIM) / (256 * 8), 256, 0, stream>>>(hs, xbf);

  dim3 g1(I2 / 64, HDIM / 64, NEXP);
  k_tc<<<g1, 256, 0, stream>>>(gup, w1t, HDIM, I2);
  dim3 g2(HDIM / 64, IDIM / 64, NEXP);
  k_tc<<<g2, 256, 0, stream>>>(dwn, w2t, IDIM, HDIM);

  k_gemm1<<<dim3(1024), 512, 0, stream>>>(xbf, w1t, gupb, rw, inter);

  k_gemm2<<<dim3(256), 512, 0, stream>>>(inter, w2t, part);

  k_reduce<<<dim3(NTOK * HDIM / 1024), 256, 0, stream>>>(part, dwnb, rw, out);
}

// Round 15
// 557.243 us; speedup vs baseline: 1.0845x; 1.0002x over previous
//
#include <hip/hip_runtime.h>
#include <cstdint>
#include <cstddef>

#define ALPHA 1.702f
#define LIMIT 7.0f

#define NTOK 2048
#define HDIM 2048
#define IDIM 2048
#define I2   4096
#define NEXP 8

typedef float f32x4 __attribute__((ext_vector_type(4)));
typedef short bf16x8 __attribute__((ext_vector_type(8)));
typedef unsigned short u16;

__device__ __forceinline__ u16 f2bf(float f) {
  unsigned u = __float_as_uint(f);
  u += 0x7fffu + ((u >> 16) & 1u);   // RNE
  return (u16)(u >> 16);
}

__device__ __forceinline__ float bf2f(u16 b) {
  return __uint_as_float(((unsigned)b) << 16);
}

__device__ __forceinline__ void gload_lds16(const void* g, void* l) {
  __builtin_amdgcn_global_load_lds(
      (const __attribute__((address_space(1))) void*)g,
      (__attribute__((address_space(3))) void*)l, 16, 0, 0);
}

#define BARRIER() do { asm volatile("" ::: "memory"); __builtin_amdgcn_s_barrier(); asm volatile("" ::: "memory"); } while (0)
#define VMCNT(n)  asm volatile("s_waitcnt vmcnt(" #n ")" ::: "memory")

// ---------------- x: fp32 -> bf16 ----------------
__global__ __launch_bounds__(256) void k_cvt(const float* __restrict__ in,
                                             u16* __restrict__ out) {
  int i = blockIdx.x * blockDim.x + threadIdx.x;
  const float4* p = (const float4*)in + (size_t)i * 2;
  float4 a = p[0], b = p[1];
  union { u16 s[8]; uint4 v; } o;
  o.s[0] = f2bf(a.x); o.s[1] = f2bf(a.y); o.s[2] = f2bf(a.z); o.s[3] = f2bf(a.w);
  o.s[4] = f2bf(b.x); o.s[5] = f2bf(b.y); o.s[6] = f2bf(b.z); o.s[7] = f2bf(b.w);
  ((uint4*)out)[i] = o.v;
}

// ------------- transpose + convert: (R,C) fp32 -> (C,R) bf16, 64x64 tiles (r12-verified) -------------
__global__ __launch_bounds__(256) void k_tc(const float* __restrict__ in,
                                            u16* __restrict__ out, int R, int C) {
  __shared__ float tile[64][65];
  const size_t mo = (size_t)blockIdx.z * R * C;
  const float* ip = in + mo;
  u16* op = out + mo;
  const int c0 = blockIdx.x * 64, r0 = blockIdx.y * 64;
  const int t = threadIdx.x;
  const int tr = t >> 4;
  const int tc = (t & 15) * 4;
#pragma unroll
  for (int i = 0; i < 4; ++i) {
    float4 v = *(const float4*)&ip[(size_t)(r0 + tr + i * 16) * C + c0 + tc];
    tile[tr + i * 16][tc] = v.x; tile[tr + i * 16][tc + 1] = v.y;
    tile[tr + i * 16][tc + 2] = v.z; tile[tr + i * 16][tc + 3] = v.w;
  }
  __syncthreads();
  const int cc = t >> 2;
  const int rb = (t & 3) * 8;
#pragma unroll
  for (int i = 0; i < 2; ++i) {
    int r = rb + i * 32;
    union { u16 s[8]; uint4 v; } o;
#pragma unroll
    for (int j = 0; j < 8; ++j) o.s[j] = f2bf(tile[r + j][cc]);
    *(uint4*)&op[(size_t)(c0 + cc) * R + r0 + r] = o.v;
  }
}

// ======================= 256x256 8-wave 8-phase GEMM core (r5/r14 skeleton) =======================
#define MFMA_Q(mh, nh, bb) \
  _Pragma("unroll") for (int ks = 0; ks < 2; ++ks) \
  _Pragma("unroll") for (int mm = 0; mm < 4; ++mm) \
  _Pragma("unroll") for (int nn = 0; nn < 2; ++nn) \
    acc[(mh)*4+mm][(nh)*2+nn] = __builtin_amdgcn_mfma_f32_16x16x32_bf16( \
        a[mm][ks], (bb)[nn][ks], acc[(mh)*4+mm][(nh)*2+nn], 0, 0, 0);

// ---------------- GEMM1: gate_up + activation + rw fold ----------------
__global__ __launch_bounds__(512, 2) void k_gemm1(const u16* __restrict__ xbf,
                                                  const u16* __restrict__ w1t,
                                                  const float* __restrict__ gub,
                                                  const float* __restrict__ rw,
                                                  u16* __restrict__ inter) {
  __shared__ __align__(16) u16 Als[4][128 * 64];
  __shared__ __align__(16) u16 Bls[4][128 * 64];

  const int bid = (int)blockIdx.x;
  const int L = (bid & 7) * 128 + (bid >> 3);
  const int mtile = L & 7, ntile = (L >> 3) & 15, e = L >> 7;
  const int row0 = mtile * 256, col0 = ntile * 256;
  const u16* A = xbf;
  const u16* B = w1t + (size_t)e * I2 * HDIM;

  const int tid = threadIdx.x;
  const int w = tid >> 6, lane = tid & 63;
  const int wr = w >> 2, wc = w & 3;
  const int rrow = lane & 15, klane = lane >> 4;
  const int sA = (wr * 64 + rrow) * 64;
  const int sB = (wc * 32 + rrow) * 64;
  int kofs[2];
  kofs[0] = ((klane ^ (rrow & 7)) << 3);
  kofs[1] = (((4 + klane) ^ (rrow & 7)) << 3);

  auto stA = [&](int reg, int h, int k0) {
#pragma unroll
    for (int j = 0; j < 2; ++j) {
      int c = (w * 2 + j) * 64 + lane;
      int r = c >> 3, gg = c & 7;
      int ksw = ((gg ^ (r & 7)) << 3);
      int R = ((r >> 6) << 7) + h * 64 + (r & 63);
      gload_lds16(A + (size_t)(row0 + R) * HDIM + k0 + ksw,
                  &Als[reg][(size_t)(w * 2 + j) * 512]);
    }
  };
  auto stB = [&](int reg, int h, int k0) {
#pragma unroll
    for (int j = 0; j < 2; ++j) {
      int c = (w * 2 + j) * 64 + lane;
      int r = c >> 3, gg = c & 7;
      int ksw = ((gg ^ (r & 7)) << 3);
      int C = ((r >> 5) << 6) + h * 32 + (r & 31);
      gload_lds16(B + (size_t)(col0 + C) * HDIM + k0 + ksw,
                  &Bls[reg][(size_t)(w * 2 + j) * 512]);
    }
  };

  f32x4 acc[8][4];
#pragma unroll
  for (int i = 0; i < 8; ++i)
#pragma unroll
    for (int j = 0; j < 4; ++j) acc[i][j] = (f32x4){0.f, 0.f, 0.f, 0.f};

  bf16x8 a[4][2], b0[2][2], b1[2][2];
  auto rdA = [&](int reg) {
#pragma unroll
    for (int mm = 0; mm < 4; ++mm)
#pragma unroll
      for (int ks = 0; ks < 2; ++ks)
        a[mm][ks] = *(const bf16x8*)&Als[reg][sA + mm * 1024 + kofs[ks]];
  };
  auto rdB0 = [&](int reg) {
#pragma unroll
    for (int nn = 0; nn < 2; ++nn)
#pragma unroll
      for (int ks = 0; ks < 2; ++ks)
        b0[nn][ks] = *(const bf16x8*)&Bls[reg][sB + nn * 1024 + kofs[ks]];
  };
  auto rdB1 = [&](int reg) {
#pragma unroll
    for (int nn = 0; nn < 2; ++nn)
#pragma unroll
      for (int ks = 0; ks < 2; ++ks)
        b1[nn][ks] = *(const bf16x8*)&Bls[reg][sB + nn * 1024 + kofs[ks]];
  };

  stB(0, 0, 0); stB(1, 1, 0); stA(0, 0, 0); stA(1, 1, 0);
  stB(2, 0, 64); stB(3, 1, 64); stA(2, 0, 64);
  VMCNT(8);
  BARRIER();

  for (int i = 0; i < 16; ++i) {
    const int t = 2 * i;
    const int kA1 = (t + 1) * 64;
    const int kN0 = (t + 2 < 32 ? t + 2 : 31) * 64;
    const int kN1 = (t + 3 < 32 ? t + 3 : 31) * 64;

    rdA(0); rdB0(0);
    stA(3, 1, kA1);
    BARRIER();
    __builtin_amdgcn_s_setprio(1); MFMA_Q(0, 0, b0); __builtin_amdgcn_s_setprio(0);
    BARRIER();

    rdB1(1);
    stB(0, 0, kN0);
    BARRIER();
    __builtin_amdgcn_s_setprio(1); MFMA_Q(0, 1, b1); __builtin_amdgcn_s_setprio(0);
    VMCNT(10);
    BARRIER();

    rdA(1);
    stB(1, 1, kN0);
    BARRIER();
    __builtin_amdgcn_s_setprio(1); MFMA_Q(1, 0, b0); __builtin_amdgcn_s_setprio(0);
    BARRIER();

    stA(0, 0, kN0);
    BARRIER();
    __builtin_amdgcn_s_setprio(1); MFMA_Q(1, 1, b1); __builtin_amdgcn_s_setprio(0);
    VMCNT(8);
    BARRIER();

    rdA(2); rdB0(2);
    stA(1, 1, kN0);
    BARRIER();
    __builtin_amdgcn_s_setprio(1); MFMA_Q(0, 0, b0); __builtin_amdgcn_s_setprio(0);
    BARRIER();

    rdB1(3);
    stB(2, 0, kN1);
    BARRIER();
    __builtin_amdgcn_s_setprio(1); MFMA_Q(0, 1, b1); __builtin_amdgcn_s_setprio(0);
    VMCNT(10);
    BARRIER();

    rdA(3);
    stB(3, 1, kN1);
    BARRIER();
    __builtin_amdgcn_s_setprio(1); MFMA_Q(1, 0, b0); __builtin_amdgcn_s_setprio(0);
    BARRIER();

    stA(2, 0, kN1);
    BARRIER();
    __builtin_amdgcn_s_setprio(1); MFMA_Q(1, 1, b1); __builtin_amdgcn_s_setprio(0);
    VMCNT(8);
    BARRIER();
  }

  const float* bias = gub + (size_t)e * I2;
  u16* ip = inter + (size_t)e * NTOK * IDIM;
#pragma unroll
  for (int ai = 0; ai < 8; ++ai) {
    const int mh = ai >> 2, mm = ai & 3;
#pragma unroll
    for (int bj = 0; bj < 4; ++bj) {
      const int nh = bj >> 1, nn = bj & 1;
      const int col = col0 + wc * 64 + nh * 32 + nn * 16 + rrow;
      const float bv = bias[col];
#pragma unroll
      for (int r = 0; r < 4; ++r) {
        const int row = row0 + wr * 128 + mh * 64 + mm * 16 + klane * 4 + r;
        float gu = acc[ai][bj][r] + bv;
        float pg = __shfl_xor(gu, 1);
        float gate = (lane & 1) ? pg : gu;
        float up   = (lane & 1) ? gu : pg;
        gate = fminf(gate, LIMIT);
        up = fminf(fmaxf(up, -LIMIT), LIMIT);
        float glu = gate / (1.f + __expf(-ALPHA * gate));
        float val = (up + 1.f) * glu * rw[row * NEXP + e];
        if (!(lane & 1)) ip[(size_t)row * IDIM + (col >> 1)] = f2bf(val);
      }
    }
  }
}

// ---------------- GEMM2: 256x256 8-phase, split-K=4; partials stored as bf16 ----------------
__global__ __launch_bounds__(512, 2) void k_gemm2(const u16* __restrict__ inter,
                                                  const u16* __restrict__ w2t,
                                                  u16* __restrict__ part) {
  __shared__ __align__(16) u16 Als[4][128 * 64];
  __shared__ __align__(16) u16 Bls[4][128 * 64];

  const int bid = (int)blockIdx.x;
  const int L = (bid & 7) * 32 + (bid >> 3);
  const int mtile = L & 7, ntile = (L >> 3) & 7, sp = L >> 6;
  const int row0 = mtile * 256, col0 = ntile * 256;
  const int es = sp * 2;

  const int tid = threadIdx.x;
  const int w = tid >> 6, lane = tid & 63;
  const int wr = w >> 2, wc = w & 3;
  const int rrow = lane & 15, klane = lane >> 4;
  const int sA = (wr * 64 + rrow) * 64;
  const int sB = (wc * 32 + rrow) * 64;
  int kofs[2];
  kofs[0] = ((klane ^ (rrow & 7)) << 3);
  kofs[1] = (((4 + klane) ^ (rrow & 7)) << 3);

  auto stA = [&](int reg, int h, int k0) {
    const u16* Ab = inter + (size_t)(es + (k0 >> 11)) * NTOK * IDIM;
    const int kk = k0 & 2047;
#pragma unroll
    for (int j = 0; j < 2; ++j) {
      int c = (w * 2 + j) * 64 + lane;
      int r = c >> 3, gg = c & 7;
      int ksw = ((gg ^ (r & 7)) << 3);
      int R = ((r >> 6) << 7) + h * 64 + (r & 63);
      gload_lds16(Ab + (size_t)(row0 + R) * IDIM + kk + ksw,
                  &Als[reg][(size_t)(w * 2 + j) * 512]);
    }
  };
  auto stB = [&](int reg, int h, int k0) {
    const u16* Bb = w2t + (size_t)(es + (k0 >> 11)) * HDIM * IDIM;
    const int kk = k0 & 2047;
#pragma unroll
    for (int j = 0; j < 2; ++j) {
      int c = (w * 2 + j) * 64 + lane;
      int r = c >> 3, gg = c & 7;
      int ksw = ((gg ^ (r & 7)) << 3);
      int C = ((r >> 5) << 6) + h * 32 + (r & 31);
      gload_lds16(Bb + (size_t)(col0 + C) * IDIM + kk + ksw,
                  &Bls[reg][(size_t)(w * 2 + j) * 512]);
    }
  };

  f32x4 acc[8][4];
#pragma unroll
  for (int i = 0; i < 8; ++i)
#pragma unroll
    for (int j = 0; j < 4; ++j) acc[i][j] = (f32x4){0.f, 0.f, 0.f, 0.f};

  bf16x8 a[4][2], b0[2][2], b1[2][2];
  auto rdA = [&](int reg) {
#pragma unroll
    for (int mm = 0; mm < 4; ++mm)
#pragma unroll
      for (int ks = 0; ks < 2; ++ks)
        a[mm][ks] = *(const bf16x8*)&Als[reg][sA + mm * 1024 + kofs[ks]];
  };
  auto rdB0 = [&](int reg) {
#pragma unroll
    for (int nn = 0; nn < 2; ++nn)
#pragma unroll
      for (int ks = 0; ks < 2; ++ks)
        b0[nn][ks] = *(const bf16x8*)&Bls[reg][sB + nn * 1024 + kofs[ks]];
  };
  auto rdB1 = [&](int reg) {
#pragma unroll
    for (int nn = 0; nn < 2; ++nn)
#pragma unroll
      for (int ks = 0; ks < 2; ++ks)
        b1[nn][ks] = *(const bf16x8*)&Bls[reg][sB + nn * 1024 + kofs[ks]];
  };

  stB(0, 0, 0); stB(1, 1, 0); stA(0, 0, 0); stA(1, 1, 0);
  stB(2, 0, 64); stB(3, 1, 64); stA(2, 0, 64);
  VMCNT(8);
  BARRIER();

  for (int i = 0; i < 32; ++i) {
    const int t = 2 * i;
    const int kA1 = (t + 1) * 64;
    const int kN0 = (t + 2 < 64 ? t + 2 : 63) * 64;
    const int kN1 = (t + 3 < 64 ? t + 3 : 63) * 64;

    rdA(0); rdB0(0);
    stA(3, 1, kA1);
    BARRIER();
    __builtin_amdgcn_s_setprio(1); MFMA_Q(0, 0, b0); __builtin_amdgcn_s_setprio(0);
    BARRIER();

    rdB1(1);
    stB(0, 0, kN0);
    BARRIER();
    __builtin_amdgcn_s_setprio(1); MFMA_Q(0, 1, b1); __builtin_amdgcn_s_setprio(0);
    VMCNT(10);
    BARRIER();

    rdA(1);
    stB(1, 1, kN0);
    BARRIER();
    __builtin_amdgcn_s_setprio(1); MFMA_Q(1, 0, b0); __builtin_amdgcn_s_setprio(0);
    BARRIER();

    stA(0, 0, kN0);
    BARRIER();
    __builtin_amdgcn_s_setprio(1); MFMA_Q(1, 1, b1); __builtin_amdgcn_s_setprio(0);
    VMCNT(8);
    BARRIER();

    rdA(2); rdB0(2);
    stA(1, 1, kN0);
    BARRIER();
    __builtin_amdgcn_s_setprio(1); MFMA_Q(0, 0, b0); __builtin_amdgcn_s_setprio(0);
    BARRIER();

    rdB1(3);
    stB(2, 0, kN1);
    BARRIER();
    __builtin_amdgcn_s_setprio(1); MFMA_Q(0, 1, b1); __builtin_amdgcn_s_setprio(0);
    VMCNT(10);
    BARRIER();

    rdA(3);
    stB(3, 1, kN1);
    BARRIER();
    __builtin_amdgcn_s_setprio(1); MFMA_Q(1, 0, b0); __builtin_amdgcn_s_setprio(0);
    BARRIER();

    stA(2, 0, kN1);
    BARRIER();
    __builtin_amdgcn_s_setprio(1); MFMA_Q(1, 1, b1); __builtin_amdgcn_s_setprio(0);
    VMCNT(8);
    BARRIER();
  }

  u16* pp = part + (size_t)sp * NTOK * HDIM;
#pragma unroll
  for (int ai = 0; ai < 8; ++ai) {
    const int mh = ai >> 2, mm = ai & 3;
#pragma unroll
    for (int bj = 0; bj < 4; ++bj) {
      const int nh = bj >> 1, nn = bj & 1;
      const int col = col0 + wc * 64 + nh * 32 + nn * 16 + rrow;
#pragma unroll
      for (int r = 0; r < 4; ++r) {
        const int row = row0 + wr * 128 + mh * 64 + mm * 16 + klane * 4 + r;
        pp[(size_t)row * HDIM + col] = f2bf(acc[ai][bj][r]);
      }
    }
  }
}

// ---------------- reduce: out = sum_splits bf16_partial + sum_e rw*down_bias ----------------
__global__ __launch_bounds__(256) void k_reduce(const u16* __restrict__ part,
                                                const float* __restrict__ dbias,
                                                const float* __restrict__ rw,
                                                float* __restrict__ out) {
  const int i = blockIdx.x * 256 + threadIdx.x;   // ushort8 index
  const int i8 = i * 8;
  const int n = i8 >> 11;
  const int h = i8 & 2047;
  const size_t MSZ = (size_t)NTOK * HDIM / 8;     // uint4 units per split
  const uint4* p = (const uint4*)part;
  float s[8] = {0.f, 0.f, 0.f, 0.f, 0.f, 0.f, 0.f, 0.f};
#pragma unroll
  for (int sp = 0; sp < 4; ++sp) {
    union { uint4 v; u16 u[8]; } x;
    x.v = p[i + (size_t)sp * MSZ];
#pragma unroll
    for (int j = 0; j < 8; ++j) s[j] += bf2f(x.u[j]);
  }
#pragma unroll
  for (int e = 0; e < NEXP; ++e) {
    float rwe = rw[n * NEXP + e];
    float4 d0 = *(const float4*)&dbias[(size_t)e * HDIM + h];
    float4 d1 = *(const float4*)&dbias[(size_t)e * HDIM + h + 4];
    s[0] += rwe * d0.x; s[1] += rwe * d0.y; s[2] += rwe * d0.z; s[3] += rwe * d0.w;
    s[4] += rwe * d1.x; s[5] += rwe * d1.y; s[6] += rwe * d1.z; s[7] += rwe * d1.w;
  }
  float4 o0 = {s[0], s[1], s[2], s[3]};
  float4 o1 = {s[4], s[5], s[6], s[7]};
  *(float4*)&out[i8] = o0;
  *(float4*)&out[i8 + 4] = o1;
}

extern "C" void kernel_launch(void* const* d_in, const int* in_sizes, int n_in,
                              void* d_out, int out_size, void* d_ws, size_t ws_size,
                              hipStream_t stream) {
  const float* hs   = (const float*)d_in[0];
  const float* rw   = (const float*)d_in[1];
  const float* gup  = (const float*)d_in[2];
  const float* gupb = (const float*)d_in[3];
  const float* dwn  = (const float*)d_in[4];
  const float* dwnb = (const float*)d_in[5];
  float* out = (float*)d_out;

  u16* xbf   = (u16*)d_ws;
  u16* w1t   = xbf + (size_t)NTOK * HDIM;
  u16* w2t   = w1t + (size_t)NEXP * I2 * HDIM;
  u16* inter = w2t + (size_t)NEXP * HDIM * IDIM;
  u16* part  = w1t;   // 4 x 8MB bf16 partials in dead w1t region
  size_t need = ((size_t)NTOK * HDIM + (size_t)NEXP * I2 * HDIM +
                 (size_t)NEXP * HDIM * IDIM + (size_t)NEXP * NTOK * IDIM) * 2;
  if (ws_size < need) return;

  k_cvt<<<(NTOK * HDIM) / (256 * 8), 256, 0, stream>>>(hs, xbf);

  dim3 g1(I2 / 64, HDIM / 64, NEXP);
  k_tc<<<g1, 256, 0, stream>>>(gup, w1t, HDIM, I2);
  dim3 g2(HDIM / 64, IDIM / 64, NEXP);
  k_tc<<<g2, 256, 0, stream>>>(dwn, w2t, IDIM, HDIM);

  k_gemm1<<<dim3(1024), 512, 0, stream>>>(xbf, w1t, gupb, rw, inter);

  k_gemm2<<<dim3(256), 512, 0, stream>>>(inter, w2t, part);

  k_reduce<<<dim3(NTOK * HDIM / (256 * 8)), 256, 0, stream>>>(part, dwnb, rw, out);
}

// Round 16
// 552.355 us; speedup vs baseline: 1.0941x; 1.0088x over previous
//
#include <hip/hip_runtime.h>
#include <cstdint>
#include <cstddef>

#define ALPHA 1.702f
#define LIMIT 7.0f

#define NTOK 2048
#define HDIM 2048
#define IDIM 2048
#define I2   4096
#define NEXP 8

typedef float f32x4 __attribute__((ext_vector_type(4)));
typedef short bf16x8 __attribute__((ext_vector_type(8)));
typedef unsigned short u16;

__device__ __forceinline__ u16 f2bf(float f) {
  unsigned u = __float_as_uint(f);
  u += 0x7fffu + ((u >> 16) & 1u);   // RNE
  return (u16)(u >> 16);
}

__device__ __forceinline__ float bf2f(u16 b) {
  return __uint_as_float(((unsigned)b) << 16);
}

__device__ __forceinline__ void gload_lds16(const void* g, void* l) {
  __builtin_amdgcn_global_load_lds(
      (const __attribute__((address_space(1))) void*)g,
      (__attribute__((address_space(3))) void*)l, 16, 0, 0);
}

#define BARRIER() do { asm volatile("" ::: "memory"); __builtin_amdgcn_s_barrier(); asm volatile("" ::: "memory"); } while (0)
#define VMCNT(n)  asm volatile("s_waitcnt vmcnt(" #n ")" ::: "memory")

// ---------------- x: fp32 -> bf16 ----------------
__global__ __launch_bounds__(256) void k_cvt(const float* __restrict__ in,
                                             u16* __restrict__ out) {
  int i = blockIdx.x * blockDim.x + threadIdx.x;
  const float4* p = (const float4*)in + (size_t)i * 2;
  float4 a = p[0], b = p[1];
  union { u16 s[8]; uint4 v; } o;
  o.s[0] = f2bf(a.x); o.s[1] = f2bf(a.y); o.s[2] = f2bf(a.z); o.s[3] = f2bf(a.w);
  o.s[4] = f2bf(b.x); o.s[5] = f2bf(b.y); o.s[6] = f2bf(b.z); o.s[7] = f2bf(b.w);
  ((uint4*)out)[i] = o.v;
}

// ------------- transpose + convert: (R,C) fp32 -> (C,R) bf16, 64x64 tiles (r12-verified) -------------
__global__ __launch_bounds__(256) void k_tc(const float* __restrict__ in,
                                            u16* __restrict__ out, int R, int C) {
  __shared__ float tile[64][65];
  const size_t mo = (size_t)blockIdx.z * R * C;
  const float* ip = in + mo;
  u16* op = out + mo;
  const int c0 = blockIdx.x * 64, r0 = blockIdx.y * 64;
  const int t = threadIdx.x;
  const int tr = t >> 4;
  const int tc = (t & 15) * 4;
#pragma unroll
  for (int i = 0; i < 4; ++i) {
    float4 v = *(const float4*)&ip[(size_t)(r0 + tr + i * 16) * C + c0 + tc];
    tile[tr + i * 16][tc] = v.x; tile[tr + i * 16][tc + 1] = v.y;
    tile[tr + i * 16][tc + 2] = v.z; tile[tr + i * 16][tc + 3] = v.w;
  }
  __syncthreads();
  const int cc = t >> 2;
  const int rb = (t & 3) * 8;
#pragma unroll
  for (int i = 0; i < 2; ++i) {
    int r = rb + i * 32;
    union { u16 s[8]; uint4 v; } o;
#pragma unroll
    for (int j = 0; j < 8; ++j) o.s[j] = f2bf(tile[r + j][cc]);
    *(uint4*)&op[(size_t)(c0 + cc) * R + r0 + r] = o.v;
  }
}

// ======================= 256x256 8-wave 8-phase GEMM core (r5/r14 skeleton) =======================
#define MFMA_Q(mh, nh, bb) \
  _Pragma("unroll") for (int ks = 0; ks < 2; ++ks) \
  _Pragma("unroll") for (int mm = 0; mm < 4; ++mm) \
  _Pragma("unroll") for (int nn = 0; nn < 2; ++nn) \
    acc[(mh)*4+mm][(nh)*2+nn] = __builtin_amdgcn_mfma_f32_16x16x32_bf16( \
        a[mm][ks], (bb)[nn][ks], acc[(mh)*4+mm][(nh)*2+nn], 0, 0, 0);

// ---------------- GEMM1: gate_up + activation + rw fold ----------------
__global__ __launch_bounds__(512, 2) void k_gemm1(const u16* __restrict__ xbf,
                                                  const u16* __restrict__ w1t,
                                                  const float* __restrict__ gub,
                                                  const float* __restrict__ rw,
                                                  u16* __restrict__ inter) {
  __shared__ __align__(16) u16 Als[4][128 * 64];
  __shared__ __align__(16) u16 Bls[4][128 * 64];

  const int bid = (int)blockIdx.x;
  const int L = (bid & 7) * 128 + (bid >> 3);
  const int mtile = L & 7, ntile = (L >> 3) & 15, e = L >> 7;
  const int row0 = mtile * 256, col0 = ntile * 256;
  const u16* A = xbf;
  const u16* B = w1t + (size_t)e * I2 * HDIM;

  const int tid = threadIdx.x;
  const int w = tid >> 6, lane = tid & 63;
  const int wr = w >> 2, wc = w & 3;
  const int rrow = lane & 15, klane = lane >> 4;
  const int sA = (wr * 64 + rrow) * 64;
  const int sB = (wc * 32 + rrow) * 64;
  int kofs[2];
  kofs[0] = ((klane ^ (rrow & 7)) << 3);
  kofs[1] = (((4 + klane) ^ (rrow & 7)) << 3);

  auto stA = [&](int reg, int h, int k0) {
#pragma unroll
    for (int j = 0; j < 2; ++j) {
      int c = (w * 2 + j) * 64 + lane;
      int r = c >> 3, gg = c & 7;
      int ksw = ((gg ^ (r & 7)) << 3);
      int R = ((r >> 6) << 7) + h * 64 + (r & 63);
      gload_lds16(A + (size_t)(row0 + R) * HDIM + k0 + ksw,
                  &Als[reg][(size_t)(w * 2 + j) * 512]);
    }
  };
  auto stB = [&](int reg, int h, int k0) {
#pragma unroll
    for (int j = 0; j < 2; ++j) {
      int c = (w * 2 + j) * 64 + lane;
      int r = c >> 3, gg = c & 7;
      int ksw = ((gg ^ (r & 7)) << 3);
      int C = ((r >> 5) << 6) + h * 32 + (r & 31);
      gload_lds16(B + (size_t)(col0 + C) * HDIM + k0 + ksw,
                  &Bls[reg][(size_t)(w * 2 + j) * 512]);
    }
  };

  f32x4 acc[8][4];
#pragma unroll
  for (int i = 0; i < 8; ++i)
#pragma unroll
    for (int j = 0; j < 4; ++j) acc[i][j] = (f32x4){0.f, 0.f, 0.f, 0.f};

  bf16x8 a[4][2], b0[2][2], b1[2][2];
  auto rdA = [&](int reg) {
#pragma unroll
    for (int mm = 0; mm < 4; ++mm)
#pragma unroll
      for (int ks = 0; ks < 2; ++ks)
        a[mm][ks] = *(const bf16x8*)&Als[reg][sA + mm * 1024 + kofs[ks]];
  };
  auto rdB0 = [&](int reg) {
#pragma unroll
    for (int nn = 0; nn < 2; ++nn)
#pragma unroll
      for (int ks = 0; ks < 2; ++ks)
        b0[nn][ks] = *(const bf16x8*)&Bls[reg][sB + nn * 1024 + kofs[ks]];
  };
  auto rdB1 = [&](int reg) {
#pragma unroll
    for (int nn = 0; nn < 2; ++nn)
#pragma unroll
      for (int ks = 0; ks < 2; ++ks)
        b1[nn][ks] = *(const bf16x8*)&Bls[reg][sB + nn * 1024 + kofs[ks]];
  };

  stB(0, 0, 0); stB(1, 1, 0); stA(0, 0, 0); stA(1, 1, 0);
  stB(2, 0, 64); stB(3, 1, 64); stA(2, 0, 64);
  VMCNT(8);
  BARRIER();

  for (int i = 0; i < 16; ++i) {
    const int t = 2 * i;
    const int kA1 = (t + 1) * 64;
    const int kN0 = (t + 2 < 32 ? t + 2 : 31) * 64;
    const int kN1 = (t + 3 < 32 ? t + 3 : 31) * 64;

    rdA(0); rdB0(0);
    stA(3, 1, kA1);
    BARRIER();
    __builtin_amdgcn_s_setprio(1); MFMA_Q(0, 0, b0); __builtin_amdgcn_s_setprio(0);
    BARRIER();

    rdB1(1);
    stB(0, 0, kN0);
    BARRIER();
    __builtin_amdgcn_s_setprio(1); MFMA_Q(0, 1, b1); __builtin_amdgcn_s_setprio(0);
    VMCNT(10);
    BARRIER();

    rdA(1);
    stB(1, 1, kN0);
    BARRIER();
    __builtin_amdgcn_s_setprio(1); MFMA_Q(1, 0, b0); __builtin_amdgcn_s_setprio(0);
    BARRIER();

    stA(0, 0, kN0);
    BARRIER();
    __builtin_amdgcn_s_setprio(1); MFMA_Q(1, 1, b1); __builtin_amdgcn_s_setprio(0);
    VMCNT(8);
    BARRIER();

    rdA(2); rdB0(2);
    stA(1, 1, kN0);
    BARRIER();
    __builtin_amdgcn_s_setprio(1); MFMA_Q(0, 0, b0); __builtin_amdgcn_s_setprio(0);
    BARRIER();

    rdB1(3);
    stB(2, 0, kN1);
    BARRIER();
    __builtin_amdgcn_s_setprio(1); MFMA_Q(0, 1, b1); __builtin_amdgcn_s_setprio(0);
    VMCNT(10);
    BARRIER();

    rdA(3);
    stB(3, 1, kN1);
    BARRIER();
    __builtin_amdgcn_s_setprio(1); MFMA_Q(1, 0, b0); __builtin_amdgcn_s_setprio(0);
    BARRIER();

    stA(2, 0, kN1);
    BARRIER();
    __builtin_amdgcn_s_setprio(1); MFMA_Q(1, 1, b1); __builtin_amdgcn_s_setprio(0);
    VMCNT(8);
    BARRIER();
  }

  const float* bias = gub + (size_t)e * I2;
  u16* ip = inter + (size_t)e * NTOK * IDIM;
#pragma unroll
  for (int ai = 0; ai < 8; ++ai) {
    const int mh = ai >> 2, mm = ai & 3;
#pragma unroll
    for (int bj = 0; bj < 4; ++bj) {
      const int nh = bj >> 1, nn = bj & 1;
      const int col = col0 + wc * 64 + nh * 32 + nn * 16 + rrow;
      const float bv = bias[col];
#pragma unroll
      for (int r = 0; r < 4; ++r) {
        const int row = row0 + wr * 128 + mh * 64 + mm * 16 + klane * 4 + r;
        float gu = acc[ai][bj][r] + bv;
        float pg = __shfl_xor(gu, 1);
        float gate = (lane & 1) ? pg : gu;
        float up   = (lane & 1) ? gu : pg;
        gate = fminf(gate, LIMIT);
        up = fminf(fmaxf(up, -LIMIT), LIMIT);
        float glu = gate / (1.f + __expf(-ALPHA * gate));
        float val = (up + 1.f) * glu * rw[row * NEXP + e];
        if (!(lane & 1)) ip[(size_t)row * IDIM + (col >> 1)] = f2bf(val);
      }
    }
  }
}

// ---------------- GEMM2: 256x256 8-phase, split-K=4; partials stored as bf16 ----------------
__global__ __launch_bounds__(512, 2) void k_gemm2(const u16* __restrict__ inter,
                                                  const u16* __restrict__ w2t,
                                                  u16* __restrict__ part) {
  __shared__ __align__(16) u16 Als[4][128 * 64];
  __shared__ __align__(16) u16 Bls[4][128 * 64];

  const int bid = (int)blockIdx.x;
  const int L = (bid & 7) * 32 + (bid >> 3);
  const int mtile = L & 7, ntile = (L >> 3) & 7, sp = L >> 6;
  const int row0 = mtile * 256, col0 = ntile * 256;
  const int es = sp * 2;

  const int tid = threadIdx.x;
  const int w = tid >> 6, lane = tid & 63;
  const int wr = w >> 2, wc = w & 3;
  const int rrow = lane & 15, klane = lane >> 4;
  const int sA = (wr * 64 + rrow) * 64;
  const int sB = (wc * 32 + rrow) * 64;
  int kofs[2];
  kofs[0] = ((klane ^ (rrow & 7)) << 3);
  kofs[1] = (((4 + klane) ^ (rrow & 7)) << 3);

  auto stA = [&](int reg, int h, int k0) {
    const u16* Ab = inter + (size_t)(es + (k0 >> 11)) * NTOK * IDIM;
    const int kk = k0 & 2047;
#pragma unroll
    for (int j = 0; j < 2; ++j) {
      int c = (w * 2 + j) * 64 + lane;
      int r = c >> 3, gg = c & 7;
      int ksw = ((gg ^ (r & 7)) << 3);
      int R = ((r >> 6) << 7) + h * 64 + (r & 63);
      gload_lds16(Ab + (size_t)(row0 + R) * IDIM + kk + ksw,
                  &Als[reg][(size_t)(w * 2 + j) * 512]);
    }
  };
  auto stB = [&](int reg, int h, int k0) {
    const u16* Bb = w2t + (size_t)(es + (k0 >> 11)) * HDIM * IDIM;
    const int kk = k0 & 2047;
#pragma unroll
    for (int j = 0; j < 2; ++j) {
      int c = (w * 2 + j) * 64 + lane;
      int r = c >> 3, gg = c & 7;
      int ksw = ((gg ^ (r & 7)) << 3);
      int C = ((r >> 5) << 6) + h * 32 + (r & 31);
      gload_lds16(Bb + (size_t)(col0 + C) * IDIM + kk + ksw,
                  &Bls[reg][(size_t)(w * 2 + j) * 512]);
    }
  };

  f32x4 acc[8][4];
#pragma unroll
  for (int i = 0; i < 8; ++i)
#pragma unroll
    for (int j = 0; j < 4; ++j) acc[i][j] = (f32x4){0.f, 0.f, 0.f, 0.f};

  bf16x8 a[4][2], b0[2][2], b1[2][2];
  auto rdA = [&](int reg) {
#pragma unroll
    for (int mm = 0; mm < 4; ++mm)
#pragma unroll
      for (int ks = 0; ks < 2; ++ks)
        a[mm][ks] = *(const bf16x8*)&Als[reg][sA + mm * 1024 + kofs[ks]];
  };
  auto rdB0 = [&](int reg) {
#pragma unroll
    for (int nn = 0; nn < 2; ++nn)
#pragma unroll
      for (int ks = 0; ks < 2; ++ks)
        b0[nn][ks] = *(const bf16x8*)&Bls[reg][sB + nn * 1024 + kofs[ks]];
  };
  auto rdB1 = [&](int reg) {
#pragma unroll
    for (int nn = 0; nn < 2; ++nn)
#pragma unroll
      for (int ks = 0; ks < 2; ++ks)
        b1[nn][ks] = *(const bf16x8*)&Bls[reg][sB + nn * 1024 + kofs[ks]];
  };

  stB(0, 0, 0); stB(1, 1, 0); stA(0, 0, 0); stA(1, 1, 0);
  stB(2, 0, 64); stB(3, 1, 64); stA(2, 0, 64);
  VMCNT(8);
  BARRIER();

  for (int i = 0; i < 32; ++i) {
    const int t = 2 * i;
    const int kA1 = (t + 1) * 64;
    const int kN0 = (t + 2 < 64 ? t + 2 : 63) * 64;
    const int kN1 = (t + 3 < 64 ? t + 3 : 63) * 64;

    rdA(0); rdB0(0);
    stA(3, 1, kA1);
    BARRIER();
    __builtin_amdgcn_s_setprio(1); MFMA_Q(0, 0, b0); __builtin_amdgcn_s_setprio(0);
    BARRIER();

    rdB1(1);
    stB(0, 0, kN0);
    BARRIER();
    __builtin_amdgcn_s_setprio(1); MFMA_Q(0, 1, b1); __builtin_amdgcn_s_setprio(0);
    VMCNT(10);
    BARRIER();

    rdA(1);
    stB(1, 1, kN0);
    BARRIER();
    __builtin_amdgcn_s_setprio(1); MFMA_Q(1, 0, b0); __builtin_amdgcn_s_setprio(0);
    BARRIER();

    stA(0, 0, kN0);
    BARRIER();
    __builtin_amdgcn_s_setprio(1); MFMA_Q(1, 1, b1); __builtin_amdgcn_s_setprio(0);
    VMCNT(8);
    BARRIER();

    rdA(2); rdB0(2);
    stA(1, 1, kN0);
    BARRIER();
    __builtin_amdgcn_s_setprio(1); MFMA_Q(0, 0, b0); __builtin_amdgcn_s_setprio(0);
    BARRIER();

    rdB1(3);
    stB(2, 0, kN1);
    BARRIER();
    __builtin_amdgcn_s_setprio(1); MFMA_Q(0, 1, b1); __builtin_amdgcn_s_setprio(0);
    VMCNT(10);
    BARRIER();

    rdA(3);
    stB(3, 1, kN1);
    BARRIER();
    __builtin_amdgcn_s_setprio(1); MFMA_Q(1, 0, b0); __builtin_amdgcn_s_setprio(0);
    BARRIER();

    stA(2, 0, kN1);
    BARRIER();
    __builtin_amdgcn_s_setprio(1); MFMA_Q(1, 1, b1); __builtin_amdgcn_s_setprio(0);
    VMCNT(8);
    BARRIER();
  }

  u16* pp = part + (size_t)sp * NTOK * HDIM;
#pragma unroll
  for (int ai = 0; ai < 8; ++ai) {
    const int mh = ai >> 2, mm = ai & 3;
#pragma unroll
    for (int bj = 0; bj < 4; ++bj) {
      const int nh = bj >> 1, nn = bj & 1;
      const int col = col0 + wc * 64 + nh * 32 + nn * 16 + rrow;
#pragma unroll
      for (int r = 0; r < 4; ++r) {
        const int row = row0 + wr * 128 + mh * 64 + mm * 16 + klane * 4 + r;
        pp[(size_t)row * HDIM + col] = f2bf(acc[ai][bj][r]);
      }
    }
  }
}

// ---------------- reduce: out = sum_splits bf16_partial + sum_e rw*down_bias ----------------
__global__ __launch_bounds__(256) void k_reduce(const u16* __restrict__ part,
                                                const float* __restrict__ dbias,
                                                const float* __restrict__ rw,
                                                float* __restrict__ out) {
  const int i = blockIdx.x * 256 + threadIdx.x;   // ushort8 index
  const int i8 = i * 8;
  const int n = i8 >> 11;
  const int h = i8 & 2047;
  const size_t MSZ = (size_t)NTOK * HDIM / 8;     // uint4 units per split
  const uint4* p = (const uint4*)part;
  float s[8] = {0.f, 0.f, 0.f, 0.f, 0.f, 0.f, 0.f, 0.f};
#pragma unroll
  for (int sp = 0; sp < 4; ++sp) {
    union { uint4 v; u16 u[8]; } x;
    x.v = p[i + (size_t)sp * MSZ];
#pragma unroll
    for (int j = 0; j < 8; ++j) s[j] += bf2f(x.u[j]);
  }
#pragma unroll
  for (int e = 0; e < NEXP; ++e) {
    float rwe = rw[n * NEXP + e];
    float4 d0 = *(const float4*)&dbias[(size_t)e * HDIM + h];
    float4 d1 = *(const float4*)&dbias[(size_t)e * HDIM + h + 4];
    s[0] += rwe * d0.x; s[1] += rwe * d0.y; s[2] += rwe * d0.z; s[3] += rwe * d0.w;
    s[4] += rwe * d1.x; s[5] += rwe * d1.y; s[6] += rwe * d1.z; s[7] += rwe * d1.w;
  }
  float4 o0 = {s[0], s[1], s[2], s[3]};
  float4 o1 = {s[4], s[5], s[6], s[7]};
  *(float4*)&out[i8] = o0;
  *(float4*)&out[i8 + 4] = o1;
}

extern "C" void kernel_launch(void* const* d_in, const int* in_sizes, int n_in,
                              void* d_out, int out_size, void* d_ws, size_t ws_size,
                              hipStream_t stream) {
  const float* hs   = (const float*)d_in[0];
  const float* rw   = (const float*)d_in[1];
  const float* gup  = (const float*)d_in[2];
  const float* gupb = (const float*)d_in[3];
  const float* dwn  = (const float*)d_in[4];
  const float* dwnb = (const float*)d_in[5];
  float* out = (float*)d_out;

  u16* xbf   = (u16*)d_ws;
  u16* w1t   = xbf + (size_t)NTOK * HDIM;
  u16* w2t   = w1t + (size_t)NEXP * I2 * HDIM;
  u16* inter = w2t + (size_t)NEXP * HDIM * IDIM;
  u16* part  = w1t;   // 4 x 8MB bf16 partials in dead w1t region
  size_t need = ((size_t)NTOK * HDIM + (size_t)NEXP * I2 * HDIM +
                 (size_t)NEXP * HDIM * IDIM + (size_t)NEXP * NTOK * IDIM) * 2;
  if (ws_size < need) return;

  k_cvt<<<(NTOK * HDIM) / (256 * 8), 256, 0, stream>>>(hs, xbf);

  // w2t transpose FIRST, then w1t: gemm1's 128MB B-matrix is written immediately
  // before gemm1 reads it -> maximal L3 residency (no 128MB of w2t-transpose
  // traffic in between to evict it).
  dim3 g2(HDIM / 64, IDIM / 64, NEXP);
  k_tc<<<g2, 256, 0, stream>>>(dwn, w2t, IDIM, HDIM);
  dim3 g1(I2 / 64, HDIM / 64, NEXP);
  k_tc<<<g1, 256, 0, stream>>>(gup, w1t, HDIM, I2);

  k_gemm1<<<dim3(1024), 512, 0, stream>>>(xbf, w1t, gupb, rw, inter);

  k_gemm2<<<dim3(256), 512, 0, stream>>>(inter, w2t, part);

  k_reduce<<<dim3(NTOK * HDIM / (256 * 8)), 256, 0, stream>>>(part, dwnb, rw, out);
}